// Round 2
// baseline (46105.795 us; speedup 1.0000x reference)
//
#include <hip/hip_runtime.h>
#include <hip/hip_bf16.h>
#include <cstdint>
#include <cstddef>

#define B_ 128
#define T_ 1024
#define I_ 256
#define H_ 512
#define M_ (B_*T_)   // 131072

typedef __attribute__((ext_vector_type(4))) float floatx4;
typedef __attribute__((ext_vector_type(8))) short short8;

__device__ __forceinline__ unsigned short f2bf(float f) {
    union { float f; unsigned u; } v; v.f = f;
    unsigned r = v.u + 0x7FFFu + ((v.u >> 16) & 1u);
    return (unsigned short)(r >> 16);
}

// ---------------- cast fp32 -> bf16 (vectorized by 4) ----------------
__global__ __launch_bounds__(256) void cast_kernel(const float* __restrict__ in,
                                                   unsigned short* __restrict__ out,
                                                   int n4) {
    int i = blockIdx.x * 256 + threadIdx.x;
    if (i >= n4) return;
    float4 f = ((const float4*)in)[i];
    ushort4 o;
    o.x = f2bf(f.x); o.y = f2bf(f.y); o.z = f2bf(f.z); o.w = f2bf(f.w);
    ((ushort4*)out)[i] = o;
}

// ---------------- zero hx + flags (uint4 granularity) ----------------
__global__ __launch_bounds__(256) void init_zero(uint4* __restrict__ p, int n) {
    int i = blockIdx.x * 256 + threadIdx.x;
    if (i < n) p[i] = make_uint4(0, 0, 0, 0);
}

// ---------------- write h0 into hx buffer 0 (rows 0,1 of each group) ----------------
__global__ __launch_bounds__(256) void init_h0(const float* __restrict__ h0,
                                               unsigned short* __restrict__ hx) {
    int e = blockIdx.x * 256 + threadIdx.x;   // 65536 = B_*H_
    int b = e >> 9;
    int j = e & 511;
    int g = b >> 1;
    int m = b & 1;
    // hx[buf=0][g][m][j], layout [2][64][16][512]
    hx[((size_t)g * 16 + m) * 512 + j] = f2bf(h0[e]);
}

// ---------------- igates GEMM: out[M,H] = Xb[M,I] @ Wib[H,I]^T + bi ----------------
#define BM 128
#define BN 128
#define BK 32

__global__ __launch_bounds__(256) void gemm_igates(
    const unsigned short* __restrict__ Xb,   // [M_, I_] bf16
    const unsigned short* __restrict__ Wib,  // [H_, I_] bf16 (N x K)
    const float* __restrict__ bi,            // [H_]
    float* __restrict__ out)                 // [M_, H_] fp32
{
    __shared__ unsigned short As[BM * BK];
    __shared__ unsigned short Bs[BN * BK];
    const int tid  = threadIdx.x;
    const int wave = tid >> 6;
    const int lane = tid & 63;
    const int quad = lane >> 4;
    const int l16  = lane & 15;
    const int bm = blockIdx.x;
    const int bn = blockIdx.y;
    const int wm = (wave >> 1) * 64;
    const int wn = (wave & 1) * 64;

    floatx4 acc[4][4] = {};

    for (int k0 = 0; k0 < I_; k0 += BK) {
        #pragma unroll
        for (int it = 0; it < 2; ++it) {
            int c   = it * 256 + tid;
            int row = c >> 2;
            int col = (c & 3) * 8;
            const unsigned short* ga = Xb  + (size_t)(bm * BM + row) * I_ + k0 + col;
            const unsigned short* gb = Wib + (size_t)(bn * BN + row) * I_ + k0 + col;
            int base = (it * 256 + wave * 64) * 8;
            __builtin_amdgcn_global_load_lds(
                (const __attribute__((address_space(1))) void*)ga,
                (__attribute__((address_space(3))) void*)(As + base), 16, 0, 0);
            __builtin_amdgcn_global_load_lds(
                (const __attribute__((address_space(1))) void*)gb,
                (__attribute__((address_space(3))) void*)(Bs + base), 16, 0, 0);
        }
        __syncthreads();

        short8 af[4], bfr[4];
        #pragma unroll
        for (int i = 0; i < 4; ++i) {
            af[i]  = *(const short8*)(As + (wm + i * 16 + l16) * BK + quad * 8);
            bfr[i] = *(const short8*)(Bs + (wn + i * 16 + l16) * BK + quad * 8);
        }
        #pragma unroll
        for (int mi = 0; mi < 4; ++mi)
            #pragma unroll
            for (int ni = 0; ni < 4; ++ni)
                acc[mi][ni] = __builtin_amdgcn_mfma_f32_16x16x32_bf16(
                    af[mi], bfr[ni], acc[mi][ni], 0, 0, 0);
        __syncthreads();
    }

    #pragma unroll
    for (int mi = 0; mi < 4; ++mi) {
        #pragma unroll
        for (int ni = 0; ni < 4; ++ni) {
            int col = bn * BN + wn + ni * 16 + l16;
            float bv = bi[col];
            #pragma unroll
            for (int r = 0; r < 4; ++r) {
                int row = bm * BM + wm + mi * 16 + quad * 4 + r;
                out[(size_t)row * H_ + col] = acc[mi][ni][r] + bv;
            }
        }
    }
}

// ---------------- cooperative scan: 64 groups x 4-way j-split = 256 blocks ----------------
// Block (g,k): batches {2g, 2g+1}, output columns [128k, 128k+128).
// Wh slice resident in VGPRs: 16 B-frags/wave = 64 VGPRs/lane.
// h exchanged via hx[2][64][16][512] bf16 (double-buffered), per-block monotone flags.
__global__ __launch_bounds__(512, 2) void scan_mfma(
    const unsigned short* __restrict__ Whb,  // [512][512] bf16 row-major (j,k)
    const float* __restrict__ bh,            // [512]
    float* __restrict__ out,                 // [B][T][H] fp32: igates in, h out
    unsigned short* __restrict__ hx,         // [2][64][16][512] bf16
    unsigned int* __restrict__ flags,        // [64][4]
    float* __restrict__ hlast)               // [B][H]
{
    const int tid  = threadIdx.x;
    const int wv   = tid >> 6;        // 0..7
    const int lane = tid & 63;
    const int quad = lane >> 4;
    const int l16  = lane & 15;
    const int bb = blockIdx.x;
    const int r  = bb & 7;            // XCD (heuristic: blockIdx % 8)
    const int s  = bb >> 3;
    const int k  = s & 3;             // member within group (j-split)
    const int gg = s >> 2;            // 0..7
    const int g  = gg * 8 + r;        // group 0..63 (all 4 members same XCD)
    const int b0 = 2 * g, b1 = 2 * g + 1;
    const int j0 = k * 128;
    const int j  = j0 + wv * 16 + l16;   // this wave's n-tile column

    // resident weight fragments: B[n=l16][k=quad*8+i] from Whb row j
    short8 wfrag[16];
    const unsigned short* wrow = Whb + (size_t)j * 512;
    #pragma unroll
    for (int kt = 0; kt < 16; ++kt)
        wfrag[kt] = *(const short8*)(wrow + kt * 32 + quad * 8);

    const float bj = bh[j];
    float* o0p = out + (size_t)b0 * T_ * H_ + j;
    float* o1p = out + (size_t)b1 * T_ * H_ + j;
    unsigned int* myflag = flags + g * 4 + k;
    const unsigned int* peer[3];
    {
        int pi = 0;
        #pragma unroll
        for (int p = 0; p < 4; ++p) if (p != k) peer[pi++] = flags + g * 4 + p;
    }

    for (int t = 0; t < T_; ++t) {
        // prefetch igates for this step (hidden under spin + mfma)
        float ig0 = 0.f, ig1 = 0.f;
        if (quad == 0) {
            ig0 = o0p[(size_t)t * H_];
            ig1 = o1p[(size_t)t * H_];
        }

        // wait for peers' h^t (acquire: invalidates this CU's L1)
        if (t > 0 && tid < 3) {
            const unsigned int* fp = peer[tid];
            while (__hip_atomic_load(fp, __ATOMIC_ACQUIRE, __HIP_MEMORY_SCOPE_AGENT)
                   < (unsigned)t) { }
        }
        __syncthreads();

        // A-frags from hx[t&1][g]; rows m>=2 are permanent zeros
        const unsigned short* hsrc =
            hx + (((size_t)(t & 1) * 64 + g) * 16 + l16) * 512;
        floatx4 acc = {0.f, 0.f, 0.f, 0.f};
        #pragma unroll
        for (int kt = 0; kt < 16; ++kt) {
            short8 a = *(const short8*)(hsrc + kt * 32 + quad * 8);
            acc = __builtin_amdgcn_mfma_f32_16x16x32_bf16(a, wfrag[kt], acc, 0, 0, 0);
        }

        // epilogue: D[row=batch][col=l16]; quad0 regs 0,1 hold batches b0,b1
        if (quad == 0) {
            float h0v = 1.f / (1.f + __expf(-(acc[0] + ig0 + bj)));
            float h1v = 1.f / (1.f + __expf(-(acc[1] + ig1 + bj)));
            o0p[(size_t)t * H_] = h0v;
            o1p[(size_t)t * H_] = h1v;
            unsigned short* hdst =
                hx + (((size_t)((t + 1) & 1) * 64 + g) * 16) * 512;
            hdst[j]       = f2bf(h0v);
            hdst[512 + j] = f2bf(h1v);
            if (t == T_ - 1) {
                hlast[(size_t)b0 * H_ + j] = h0v;
                hlast[(size_t)b1 * H_ + j] = h1v;
            }
        }
        __threadfence();          // drain stores to L2 (device-visible)
        __syncthreads();
        if (tid == 0)
            __hip_atomic_store(myflag, (unsigned)(t + 1),
                               __ATOMIC_RELEASE, __HIP_MEMORY_SCOPE_AGENT);
    }
}

extern "C" void kernel_launch(void* const* d_in, const int* in_sizes, int n_in,
                              void* d_out, int out_size, void* d_ws, size_t ws_size,
                              hipStream_t stream) {
    const float* x  = (const float*)d_in[0];   // [B,T,I]
    const float* h0 = (const float*)d_in[1];   // [B,H]
    const float* Wi = (const float*)d_in[2];   // [H,I]
    const float* bi = (const float*)d_in[3];   // [H]
    const float* Wh = (const float*)d_in[4];   // [H,H]
    const float* bh = (const float*)d_in[5];   // [H]
    float* out = (float*)d_out;

    // workspace layout (all 16B-aligned)
    unsigned short* Xb    = (unsigned short*)d_ws;            // 64 MB
    unsigned short* Wib   = Xb  + (size_t)M_ * I_;            // 256 KB
    unsigned short* Whb   = Wib + (size_t)H_ * I_;            // 512 KB
    unsigned short* hx    = Whb + (size_t)H_ * H_;            // 2 MB: [2][64][16][512]
    unsigned int*   flags = (unsigned int*)(hx + (size_t)2 * 64 * 16 * 512); // 1 KB

    // casts
    cast_kernel<<<(M_ * I_ / 4 + 255) / 256, 256, 0, stream>>>(x, Xb, M_ * I_ / 4);
    cast_kernel<<<(H_ * I_ / 4 + 255) / 256, 256, 0, stream>>>(Wi, Wib, H_ * I_ / 4);
    cast_kernel<<<(H_ * H_ / 4 + 255) / 256, 256, 0, stream>>>(Wh, Whb, H_ * H_ / 4);

    // zero hx (131072 uint4) + flags (64 uint4) = 131136 uint4, then write h0
    init_zero<<<(131136 + 255) / 256, 256, 0, stream>>>((uint4*)hx, 131136);
    init_h0<<<(B_ * H_) / 256, 256, 0, stream>>>(h0, hx);

    // igates = x @ Wi^T + bi -> d_out
    dim3 ggrid(M_ / BM, H_ / BN);
    gemm_igates<<<ggrid, 256, 0, stream>>>(Xb, Wib, bi, out);

    // cooperative scan (256 blocks, guaranteed co-resident for flag sync)
    float* hlast = out + (size_t)M_ * H_;
    void* args[6];
    const unsigned short* Whb_c = Whb;
    const float* bh_c = bh;
    args[0] = (void*)&Whb_c;
    args[1] = (void*)&bh_c;
    args[2] = (void*)&out;
    args[3] = (void*)&hx;
    args[4] = (void*)&flags;
    args[5] = (void*)&hlast;
    hipLaunchCooperativeKernel((const void*)scan_mfma, dim3(256), dim3(512),
                               args, 0, stream);
}

// Round 3
// 17603.671 us; speedup vs baseline: 2.6191x; 2.6191x over previous
//
#include <hip/hip_runtime.h>
#include <hip/hip_bf16.h>
#include <cstdint>
#include <cstddef>

#define B_ 128
#define T_ 1024
#define I_ 256
#define H_ 512
#define M_ (B_*T_)   // 131072

typedef __attribute__((ext_vector_type(4))) float floatx4;
typedef __attribute__((ext_vector_type(8))) short short8;
typedef unsigned long long u64;

__device__ __forceinline__ unsigned short f2bf(float f) {
    union { float f; unsigned u; } v; v.f = f;
    unsigned r = v.u + 0x7FFFu + ((v.u >> 16) & 1u);
    return (unsigned short)(r >> 16);
}

// ---------------- cast fp32 -> bf16 (vectorized by 4) ----------------
__global__ __launch_bounds__(256) void cast_kernel(const float* __restrict__ in,
                                                   unsigned short* __restrict__ out,
                                                   int n4) {
    int i = blockIdx.x * 256 + threadIdx.x;
    if (i >= n4) return;
    float4 f = ((const float4*)in)[i];
    ushort4 o;
    o.x = f2bf(f.x); o.y = f2bf(f.y); o.z = f2bf(f.z); o.w = f2bf(f.w);
    ((ushort4*)out)[i] = o;
}

// ---------------- zero flags ----------------
__global__ __launch_bounds__(64) void init_zero(unsigned int* __restrict__ p, int n) {
    int i = blockIdx.x * 64 + threadIdx.x;
    if (i < n) p[i] = 0u;
}

// ---------------- h0 -> hx buffer 0 ([2][8][16][512]; buf0 flat == [b][j]) ----------------
__global__ __launch_bounds__(256) void init_h0(const float* __restrict__ h0,
                                               unsigned short* __restrict__ hx) {
    int e = blockIdx.x * 256 + threadIdx.x;   // 65536 = B_*H_
    hx[e] = f2bf(h0[e]);
}

// ---------------- igates GEMM: out[M,H] = Xb[M,I] @ Wib[H,I]^T + bi ----------------
#define BM 128
#define BN 128
#define BK 32

__global__ __launch_bounds__(256) void gemm_igates(
    const unsigned short* __restrict__ Xb,   // [M_, I_] bf16
    const unsigned short* __restrict__ Wib,  // [H_, I_] bf16 (N x K)
    const float* __restrict__ bi,            // [H_]
    float* __restrict__ out)                 // [M_, H_] fp32
{
    __shared__ unsigned short As[BM * BK];
    __shared__ unsigned short Bs[BN * BK];
    const int tid  = threadIdx.x;
    const int wave = tid >> 6;
    const int lane = tid & 63;
    const int quad = lane >> 4;
    const int l16  = lane & 15;
    const int bm = blockIdx.x;
    const int bn = blockIdx.y;
    const int wm = (wave >> 1) * 64;
    const int wn = (wave & 1) * 64;

    floatx4 acc[4][4] = {};

    for (int k0 = 0; k0 < I_; k0 += BK) {
        #pragma unroll
        for (int it = 0; it < 2; ++it) {
            int c   = it * 256 + tid;
            int row = c >> 2;
            int col = (c & 3) * 8;
            const unsigned short* ga = Xb  + (size_t)(bm * BM + row) * I_ + k0 + col;
            const unsigned short* gb = Wib + (size_t)(bn * BN + row) * I_ + k0 + col;
            int base = (it * 256 + wave * 64) * 8;
            __builtin_amdgcn_global_load_lds(
                (const __attribute__((address_space(1))) void*)ga,
                (__attribute__((address_space(3))) void*)(As + base), 16, 0, 0);
            __builtin_amdgcn_global_load_lds(
                (const __attribute__((address_space(1))) void*)gb,
                (__attribute__((address_space(3))) void*)(Bs + base), 16, 0, 0);
        }
        __syncthreads();

        short8 af[4], bfr[4];
        #pragma unroll
        for (int i = 0; i < 4; ++i) {
            af[i]  = *(const short8*)(As + (wm + i * 16 + l16) * BK + quad * 8);
            bfr[i] = *(const short8*)(Bs + (wn + i * 16 + l16) * BK + quad * 8);
        }
        #pragma unroll
        for (int mi = 0; mi < 4; ++mi)
            #pragma unroll
            for (int ni = 0; ni < 4; ++ni)
                acc[mi][ni] = __builtin_amdgcn_mfma_f32_16x16x32_bf16(
                    af[mi], bfr[ni], acc[mi][ni], 0, 0, 0);
        __syncthreads();
    }

    #pragma unroll
    for (int mi = 0; mi < 4; ++mi) {
        #pragma unroll
        for (int ni = 0; ni < 4; ++ni) {
            int col = bn * BN + wn + ni * 16 + l16;
            float bv = bi[col];
            #pragma unroll
            for (int r = 0; r < 4; ++r) {
                int row = bm * BM + wm + mi * 16 + quad * 4 + r;
                out[(size_t)row * H_ + col] = acc[mi][ni][r] + bv;
            }
        }
    }
}

// ---------------- cooperative scan: 8 groups x 2 blocks = 16 blocks ----------------
// Block (g = bb&7, hs = bb>>3): batches [16g,16g+16), cols [256*hs, 256*hs+256).
// Wh slice resident in VGPRs (32 frags = 128 VGPR/lane). h exchanged via
// hx[2][8][16][512] bf16 at MALL using RELAXED agent atomics (sc0 sc1, NO bulk
// cache maintenance). Ordering: stores -> s_waitcnt(0) -> barrier -> flag store.
__global__ __launch_bounds__(512, 2) void scan_mfma2(
    const unsigned short* __restrict__ Whb,  // [512][512] bf16 row-major (j,k)
    const float* __restrict__ bh,            // [512]
    float* __restrict__ out,                 // [B][T][H] fp32: igates in, h out
    unsigned short* __restrict__ hx,         // [2][8][16][512] bf16
    unsigned int* __restrict__ flags,        // [8][2]
    float* __restrict__ hlast)               // [B][H]
{
    const int tid  = threadIdx.x;
    const int w    = tid >> 6;        // wave 0..7
    const int lane = tid & 63;
    const int quad = lane >> 4;
    const int l16  = lane & 15;
    const int bb   = blockIdx.x;      // 0..15
    const int g    = bb & 7;          // group
    const int hs   = bb >> 3;         // half (col slice)
    const int jw   = hs * 256 + w * 32;   // wave col base

    // resident weight fragments: wf[nt][kt] = Wh rows (cols of C) jw+nt*16+l16
    short8 wf0[16], wf1[16];
    #pragma unroll
    for (int kt = 0; kt < 16; ++kt) {
        wf0[kt] = *(const short8*)(Whb + (size_t)(jw + l16) * 512 + kt * 32 + quad * 8);
        wf1[kt] = *(const short8*)(Whb + (size_t)(jw + 16 + l16) * 512 + kt * 32 + quad * 8);
    }
    const float bj0 = bh[jw + l16];
    const float bj1 = bh[jw + 16 + l16];

    // per-lane out/ig base offsets: row r -> batch g*16+quad*4+r, col jw+nt*16+l16
    size_t obase[4];
    #pragma unroll
    for (int r = 0; r < 4; ++r)
        obase[r] = (size_t)(g * 16 + quad * 4 + r) * T_ * H_ + jw + l16;

    unsigned int* myflag = flags + g * 2 + hs;
    unsigned int* pflag  = flags + g * 2 + (1 - hs);
    const int ownk = hs * 8;          // own k-tile range [ownk, ownk+8)
    const int prk  = 8 - ownk ? (1 - hs) * 8 : 0;  // partner base (computed below anyway)
    const int peerk = (1 - hs) * 8;

    for (int t = 0; t < T_; ++t) {
        // igates prefetch for this step (plain cached loads; overlap poll+MALL)
        float igv[4][2];
        #pragma unroll
        for (int r = 0; r < 4; ++r) {
            igv[r][0] = out[obase[r] + (size_t)t * H_];
            igv[r][1] = out[obase[r] + (size_t)t * H_ + 16];
        }

        // A-frag base for buf t&1 (u64 units): shorts offset l16*512 + kt*32 + quad*8
        const u64* ab = (const u64*)(hx + (((size_t)(t & 1) * 8 + g) * 16) * 512)
                        + l16 * 128 + quad * 2;

        short8 afr[16];
        // own half: no wait needed (own stores drained before last barrier)
        #pragma unroll
        for (int kk = 0; kk < 8; ++kk) {
            int kt = ownk + kk;
            union { u64 q[2]; short8 s; } u;
            u.q[0] = __hip_atomic_load(ab + kt * 8,     __ATOMIC_RELAXED, __HIP_MEMORY_SCOPE_AGENT);
            u.q[1] = __hip_atomic_load(ab + kt * 8 + 1, __ATOMIC_RELAXED, __HIP_MEMORY_SCOPE_AGENT);
            afr[kt] = u.s;
        }
        floatx4 acc0 = {0.f, 0.f, 0.f, 0.f};
        floatx4 acc1 = {0.f, 0.f, 0.f, 0.f};
        #pragma unroll
        for (int kk = 0; kk < 8; ++kk) {
            int kt = ownk + kk;
            acc0 = __builtin_amdgcn_mfma_f32_16x16x32_bf16(afr[kt], wf0[kt], acc0, 0, 0, 0);
            acc1 = __builtin_amdgcn_mfma_f32_16x16x32_bf16(afr[kt], wf1[kt], acc1, 0, 0, 0);
        }

        // wait for partner's step-t state (relaxed poll, no cache maintenance)
        if (t > 0) {
            while (__hip_atomic_load(pflag, __ATOMIC_RELAXED, __HIP_MEMORY_SCOPE_AGENT)
                   < (unsigned)t) { }
        }
        __atomic_signal_fence(__ATOMIC_SEQ_CST);

        // partner half
        #pragma unroll
        for (int kk = 0; kk < 8; ++kk) {
            int kt = peerk + kk;
            union { u64 q[2]; short8 s; } u;
            u.q[0] = __hip_atomic_load(ab + kt * 8,     __ATOMIC_RELAXED, __HIP_MEMORY_SCOPE_AGENT);
            u.q[1] = __hip_atomic_load(ab + kt * 8 + 1, __ATOMIC_RELAXED, __HIP_MEMORY_SCOPE_AGENT);
            afr[kt] = u.s;
        }
        #pragma unroll
        for (int kk = 0; kk < 8; ++kk) {
            int kt = peerk + kk;
            acc0 = __builtin_amdgcn_mfma_f32_16x16x32_bf16(afr[kt], wf0[kt], acc0, 0, 0, 0);
            acc1 = __builtin_amdgcn_mfma_f32_16x16x32_bf16(afr[kt], wf1[kt], acc1, 0, 0, 0);
        }

        // epilogue: D[row=quad*4+r][col=nt*16+l16]
        unsigned short* hxn = hx + (((size_t)((t + 1) & 1) * 8 + g) * 16) * 512;
        #pragma unroll
        for (int r = 0; r < 4; ++r) {
            float v0 = acc0[r] + igv[r][0] + bj0;
            float v1 = acc1[r] + igv[r][1] + bj1;
            float h0v = 1.f / (1.f + __expf(-v0));
            float h1v = 1.f / (1.f + __expf(-v1));
            out[obase[r] + (size_t)t * H_]      = h0v;
            out[obase[r] + (size_t)t * H_ + 16] = h1v;
            int m = quad * 4 + r;
            __hip_atomic_store(hxn + (size_t)m * 512 + jw + l16,      f2bf(h0v),
                               __ATOMIC_RELAXED, __HIP_MEMORY_SCOPE_AGENT);
            __hip_atomic_store(hxn + (size_t)m * 512 + jw + 16 + l16, f2bf(h1v),
                               __ATOMIC_RELAXED, __HIP_MEMORY_SCOPE_AGENT);
            if (t == T_ - 1) {
                hlast[(size_t)(g * 16 + m) * H_ + jw + l16]      = h0v;
                hlast[(size_t)(g * 16 + m) * H_ + jw + 16 + l16] = h1v;
            }
        }

        // drain own stores (per-wave), then block barrier, then publish flag
        __atomic_signal_fence(__ATOMIC_SEQ_CST);
        __builtin_amdgcn_s_waitcnt(0);
        __syncthreads();
        if (tid == 0)
            __hip_atomic_store(myflag, (unsigned)(t + 1),
                               __ATOMIC_RELAXED, __HIP_MEMORY_SCOPE_AGENT);
    }
}

extern "C" void kernel_launch(void* const* d_in, const int* in_sizes, int n_in,
                              void* d_out, int out_size, void* d_ws, size_t ws_size,
                              hipStream_t stream) {
    const float* x  = (const float*)d_in[0];   // [B,T,I]
    const float* h0 = (const float*)d_in[1];   // [B,H]
    const float* Wi = (const float*)d_in[2];   // [H,I]
    const float* bi = (const float*)d_in[3];   // [H]
    const float* Wh = (const float*)d_in[4];   // [H,H]
    const float* bh = (const float*)d_in[5];   // [H]
    float* out = (float*)d_out;

    // workspace layout (all 16B-aligned)
    unsigned short* Xb    = (unsigned short*)d_ws;            // 64 MB
    unsigned short* Wib   = Xb  + (size_t)M_ * I_;            // 256 KB
    unsigned short* Whb   = Wib + (size_t)H_ * I_;            // 512 KB
    unsigned short* hx    = Whb + (size_t)H_ * H_;            // 256 KB: [2][8][16][512]
    unsigned int*   flags = (unsigned int*)(hx + (size_t)2 * 8 * 16 * 512); // 64 B

    // casts
    cast_kernel<<<(M_ * I_ / 4 + 255) / 256, 256, 0, stream>>>(x, Xb, M_ * I_ / 4);
    cast_kernel<<<(H_ * I_ / 4 + 255) / 256, 256, 0, stream>>>(Wi, Wib, H_ * I_ / 4);
    cast_kernel<<<(H_ * H_ / 4 + 255) / 256, 256, 0, stream>>>(Wh, Whb, H_ * H_ / 4);

    // flags = 0, hx buf0 = h0 (buf1 never read before written)
    init_zero<<<1, 64, 0, stream>>>(flags, 16);
    init_h0<<<(B_ * H_) / 256, 256, 0, stream>>>(h0, hx);

    // igates = x @ Wi^T + bi -> d_out
    dim3 ggrid(M_ / BM, H_ / BN);
    gemm_igates<<<ggrid, 256, 0, stream>>>(Xb, Wib, bi, out);

    // cooperative scan (16 blocks, co-resident; fine-grained MALL sync)
    float* hlast = out + (size_t)M_ * H_;
    void* args[6];
    const unsigned short* Whb_c = Whb;
    const float* bh_c = bh;
    args[0] = (void*)&Whb_c;
    args[1] = (void*)&bh_c;
    args[2] = (void*)&out;
    args[3] = (void*)&hx;
    args[4] = (void*)&flags;
    args[5] = (void*)&hlast;
    hipLaunchCooperativeKernel((const void*)scan_mfma2, dim3(16), dim3(512),
                               args, 0, stream);
}